// Round 1
// 127.420 us; speedup vs baseline: 1.0074x; 1.0074x over previous
//
#include <hip/hip_runtime.h>
#include <hip/hip_bf16.h>

// ConvSelfAttn: B=8, N=4096, C=64, d=8. FP32 I/O.
// R14: attn K-loop software pipeline. Counters showed latency-bound (all pipes
// <25% per-SIMD): (1) kk prefetched one iter ahead (was: load->use same iter,
// full L2 latency exposed); (2) P LDS tile double-buffered, PV deferred one
// iter so the pack->ds_write->lgkm->ds_read round trip hides under the next
// tile's QK^T+exp; (3) Obuf stride 16->20 f32 + floatx4 combine reads (was
// 8-way bank conflict); launch_bounds(256,4) caps at 128 VGPR to hold the
// grid-imposed 4 waves/SIMD.

#define BB 8
#define NN 4096
#define CC 64
#define PSTRIDE 72
#define LOG2E 1.44269504088896f

typedef _Float16 f16;
typedef _Float16 half8 __attribute__((ext_vector_type(8)));
typedef _Float16 half4 __attribute__((ext_vector_type(4)));
typedef __fp16 fp16x2 __attribute__((ext_vector_type(2)));
typedef float floatx4 __attribute__((ext_vector_type(4)));

static __device__ inline half4 pack4(float a, float b, float c, float d) {
    fp16x2 lo = __builtin_amdgcn_cvt_pkrtz(a, b);
    fp16x2 hi = __builtin_amdgcn_cvt_pkrtz(c, d);
    unsigned int lou = __builtin_bit_cast(unsigned int, lo);
    unsigned int hiu = __builtin_bit_cast(unsigned int, hi);
    unsigned long long packed = (unsigned long long)lou | ((unsigned long long)hiu << 32);
    return __builtin_bit_cast(half4, packed);
}

// ws layouts (halfs):
//   Qh [B*N][8]                          Q pre-scaled by log2e
//   Kf [B][128 pair][64 lane][8]         pair-interleaved A-frags; halfs 0-3 =
//                                        even 16-key tile, 4-7 = odd; quad2 =
//                                        {1,0,0,0} (mf channel), quad3 = 0
//   Vf [B][128 kb32][4 ct][64 lane][8]   A-frags for 16x16x32 PV
//   qn2 [B*N] f32 | kn2 [B*N] f32 | Mk2 [B] f32

// ---------------- fused projection + fragment repack + norms ----------------
// grid 512 x 256 (4 waves x 16 pixels; block = 64 pixels of one batch)
__global__ __launch_bounds__(256) void proj_all_kernel(
    const float* __restrict__ x,
    const float* __restrict__ wq, const float* __restrict__ bq,
    const float* __restrict__ wk, const float* __restrict__ bk,
    const float* __restrict__ wv, const float* __restrict__ bv,
    f16* __restrict__ Qh, f16* __restrict__ Kf, f16* __restrict__ Vf,
    float* __restrict__ qn2, float* __restrict__ kn2)
{
    __shared__ alignas(16) f16 Ws[80][PSTRIDE];  // rows 0-63=V, 64-71=Q, 72-79=K
    __shared__ float Bs[80];
    __shared__ alignas(16) f16 Vs[64][68];       // [pixel][ch], pitch 68
    __shared__ alignas(16) f16 Ks[64][12];       // [pixel][ch]
    const int tid = threadIdx.x;

    for (int i = tid; i < 4096; i += 256) {
        int cin = i >> 6, cout = i & 63;
        Ws[cout][cin] = (f16)wv[i];
    }
    for (int i = tid; i < 512; i += 256) {
        int cin = i >> 3, c = i & 7;
        Ws[64 + c][cin] = (f16)(wq[i] * LOG2E);
        Ws[72 + c][cin] = (f16)wk[i];
    }
    if (tid < 80)
        Bs[tid] = (tid < 64) ? bv[tid]
                : (tid < 72 ? bq[tid - 64] * LOG2E : bk[tid - 72]);
    __syncthreads();

    const int wave = tid >> 6, lane = tid & 63;
    const int quad = lane >> 4, n16 = lane & 15;
    const long pb = (long)blockIdx.x * 64;
    const long p0 = pb + wave * 16;
    const int  b   = (int)(pb >> 12);
    const int  nnb = (int)(pb & 4095);

    half8 ax[2];
#pragma unroll
    for (int kh = 0; kh < 2; ++kh) {
        const float* xp = x + (p0 + n16) * 64 + kh * 32 + quad * 8;
        float4 x1 = *(const float4*)xp;
        float4 x2 = *(const float4*)(xp + 4);
        ax[kh][0] = (f16)x1.x; ax[kh][1] = (f16)x1.y;
        ax[kh][2] = (f16)x1.z; ax[kh][3] = (f16)x1.w;
        ax[kh][4] = (f16)x2.x; ax[kh][5] = (f16)x2.y;
        ax[kh][6] = (f16)x2.z; ax[kh][7] = (f16)x2.w;
    }

#pragma unroll
    for (int ct = 0; ct < 5; ++ct) {
        const int cout = (ct < 4) ? ct * 16 + n16 : 64 + n16;
        const float bias = Bs[cout];
        half8 b0 = *(const half8*)(&Ws[cout][quad * 8]);
        half8 b1 = *(const half8*)(&Ws[cout][32 + quad * 8]);
        floatx4 acc = {bias, bias, bias, bias};
        acc = __builtin_amdgcn_mfma_f32_16x16x32_f16(ax[0], b0, acc, 0, 0, 0);
        acc = __builtin_amdgcn_mfma_f32_16x16x32_f16(ax[1], b1, acc, 0, 0, 0);
        if (ct < 4) {
#pragma unroll
            for (int r = 0; r < 4; ++r)
                Vs[wave * 16 + quad * 4 + r][ct * 16 + n16] = (f16)acc[r];
        } else {
            float n2[4];
#pragma unroll
            for (int r = 0; r < 4; ++r) n2[r] = acc[r] * acc[r];
#pragma unroll
            for (int d = 1; d < 8; d <<= 1)
#pragma unroll
                for (int r = 0; r < 4; ++r) n2[r] += __shfl_xor(n2[r], d, 64);
            if (n16 == 0) {
#pragma unroll
                for (int r = 0; r < 4; ++r) qn2[p0 + quad * 4 + r] = n2[r];
            } else if (n16 == 8) {
#pragma unroll
                for (int r = 0; r < 4; ++r) kn2[p0 + quad * 4 + r] = n2[r];
            }
            if (n16 < 8) {
                f16* dst = Qh + (p0 + quad * 4) * 8 + n16;
#pragma unroll
                for (int r = 0; r < 4; ++r) dst[r * 8] = (f16)acc[r];
            } else {
#pragma unroll
                for (int r = 0; r < 4; ++r)
                    Ks[wave * 16 + quad * 4 + r][n16 - 8] = (f16)acc[r];
            }
        }
    }
    __syncthreads();

    // V fragment stores (2 tiles per wave), full 16B/lane
#pragma unroll
    for (int u = 0; u < 2; ++u) {
        const int tt = wave * 2 + u;
        const int kb = tt >> 2, ct = tt & 3;
        half8 v;
#pragma unroll
        for (int j = 0; j < 8; ++j)
            v[j] = Vs[kb * 32 + quad * 8 + j][ct * 16 + n16];
        const size_t kbg = (size_t)b * 128 + (nnb >> 5) + kb;
        *(half8*)(Vf + (kbg * 4 + ct) * 512 + lane * 8) = v;
    }
    // K pair-tile stores: waves 0-1 each store one pair as full 16B/lane lines
    if (wave < 2) {
        half8 kp;
#pragma unroll
        for (int e = 0; e < 2; ++e) {
            const int t = wave * 2 + e;
#pragma unroll
            for (int j = 0; j < 4; ++j) {
                f16 v = (f16)0.f;
                if (quad < 2) v = Ks[t * 16 + n16][quad * 4 + j];
                else if (quad == 2 && j == 0) v = (f16)1.f;  // mf ones channel
                kp[e * 4 + j] = v;
            }
        }
        const size_t kpg = (size_t)b * 128 + (nnb >> 5) + wave;
        *(half8*)(Kf + kpg * 512 + lane * 8) = kp;
    }
}

// ---------------- per-batch max key-norm reduce ----------------
__global__ __launch_bounds__(256) void knorm_max_kernel(
    const float* __restrict__ kn2, float* __restrict__ Mk2)
{
    __shared__ float red[4];
    const int b = blockIdx.x, tid = threadIdx.x;
    float mx = 0.f;
    for (int i = tid; i < NN; i += 256) mx = fmaxf(mx, kn2[(size_t)b * NN + i]);
#pragma unroll
    for (int d = 1; d < 64; d <<= 1) mx = fmaxf(mx, __shfl_xor(mx, d, 64));
    if ((tid & 63) == 0) red[tid >> 6] = mx;
    __syncthreads();
    if (tid == 0) Mk2[b] = fmaxf(fmaxf(red[0], red[1]), fmaxf(red[2], red[3]));
}

// ---------------- flash attention, static-max, 32 q/wave, key-split 4 ----------------
// grid B*128 = 1024 x 256 thr; wave = ks (0..3): keys [ks*1024,+1024), 16 iters.
// R14 pipeline per iter: read bp(it-1) | QK^T(it) | prefetch kk(it+1) |
// exp/pack(it) | PV(it-1) | issue av(it).
__global__ __launch_bounds__(256, 4) void attn_kernel(
    const f16* __restrict__ Qh, const f16* __restrict__ Kf,
    const f16* __restrict__ Vf,
    const float* __restrict__ qn2, const float* __restrict__ Mk2,
    const float* __restrict__ x, const float* __restrict__ gptr,
    float* __restrict__ out)
{
    // smem union: two P buffers (2 x 18432B) during K-loop; Obuf (stride-20
    // f32, 30720B) after the barrier.
    __shared__ alignas(16) char smem[36864];
    __shared__ float Ls[4][2][16];
    f16*   Pbase = (f16*)smem;
    float* Obuf  = (float*)smem;

    const int tid  = threadIdx.x;
    const int wave = tid >> 6, lane = tid & 63;
    const int quad = lane >> 4, n16 = lane & 15;
    const int ks = wave;

    const int b  = blockIdx.x & 7;
    const int qt = blockIdx.x >> 3;               // 0..127 (32-query tile)
    const size_t bN = (size_t)b * NN;

    const float mk2 = Mk2[b];

    // Q B-frags: quads 0-1 = Q data; quad2 = {-mf,0,0,0}; quad3 = 0.
    half4 bq4[2];
#pragma unroll
    for (int qt2 = 0; qt2 < 2; ++qt2) {
        const int q = qt * 32 + qt2 * 16 + n16;
        const float mf = __builtin_sqrtf(qn2[bN + q] * mk2) - 12.0f;
        half4 v = {0, 0, 0, 0};
        if (quad < 2)
            v = *(const half4*)(Qh + (bN + q) * 8 + quad * 4);
        else if (quad == 2)
            v[0] = (f16)(-mf);
        bq4[qt2] = v;
    }

    floatx4 oacc[2][4];
#pragma unroll
    for (int qt2 = 0; qt2 < 2; ++qt2)
#pragma unroll
        for (int ct = 0; ct < 4; ++ct) oacc[qt2][ct] = (floatx4){0.f, 0.f, 0.f, 0.f};
    float l_loc[2] = {0.f, 0.f};

    const f16* kfb = Kf + ((size_t)b * 128 + ks * 32) * 512 + lane * 8;
    const f16* vfb = Vf + ((size_t)b * 128 + ks * 32) * 2048 + lane * 8;
    const floatx4 zero4 = {0.f, 0.f, 0.f, 0.f};

    // per-wave P regions: buffer A at [0,18432), buffer B at [18432,36864)
    f16* PA = Pbase + wave * 2304;
    f16* PB = Pbase + 9216 + wave * 2304;

    half8 kkc0 = *(const half8*)(kfb + 0);
    half8 kkc1 = *(const half8*)(kfb + 512);
    half8 kkn0, kkn1;
    half8 av0[4], av1[4];

    // ---- iteration 0: S(0) -> PA; prefetch kk(1); issue av(0); no PV yet ----
    {
        half4 ak[4];
        ak[0] = __builtin_shufflevector(kkc0, kkc0, 0, 1, 2, 3);
        ak[1] = __builtin_shufflevector(kkc0, kkc0, 4, 5, 6, 7);
        ak[2] = __builtin_shufflevector(kkc1, kkc1, 0, 1, 2, 3);
        ak[3] = __builtin_shufflevector(kkc1, kkc1, 4, 5, 6, 7);

        kkn0 = *(const half8*)(kfb + 1024);
        kkn1 = *(const half8*)(kfb + 1536);
#pragma unroll
        for (int ct = 0; ct < 4; ++ct)
            av0[ct] = *(const half8*)(vfb + (size_t)ct * 512);
#pragma unroll
        for (int ct = 0; ct < 4; ++ct)
            av1[ct] = *(const half8*)(vfb + (size_t)(4 + ct) * 512);

        floatx4 sf[4];
#pragma unroll
        for (int qt2 = 0; qt2 < 2; ++qt2) {
#pragma unroll
            for (int t = 0; t < 4; ++t)
                sf[t] = __builtin_amdgcn_mfma_f32_16x16x16f16(ak[t], bq4[qt2], zero4, 0, 0, 0);
            float rst[4];
            f16* Pw = PA + qt2 * 1152 + n16 * PSTRIDE;
#pragma unroll
            for (int t = 0; t < 4; ++t) {
                float p0 = __builtin_exp2f(sf[t][0]);
                float p1 = __builtin_exp2f(sf[t][1]);
                float p2 = __builtin_exp2f(sf[t][2]);
                float p3 = __builtin_exp2f(sf[t][3]);
                rst[t] = (p0 + p1) + (p2 + p3);
                *(half4*)(Pw + t * 16 + quad * 4) = pack4(p0, p1, p2, p3);
            }
            l_loc[qt2] += (rst[0] + rst[1]) + (rst[2] + rst[3]);
        }
        kkc0 = kkn0; kkc1 = kkn1;
    }

    // ---- steady state: it = 1..15 ----
    for (int it = 1; it < 16; ++it) {
        f16* Pr = (it & 1) ? PA : PB;   // holds P(it-1)
        f16* Pw = (it & 1) ? PB : PA;   // receives P(it)

        // (1) read P(it-1) frags early; consumed by PV at (4)
        __asm__ volatile("s_waitcnt lgkmcnt(0)" ::: "memory");
        half8 bp[2][2];
#pragma unroll
        for (int qt2 = 0; qt2 < 2; ++qt2) {
            const f16* p = Pr + qt2 * 1152 + n16 * PSTRIDE;
            bp[qt2][0] = *(const half8*)(p + quad * 8);
            bp[qt2][1] = *(const half8*)(p + 32 + quad * 8);
        }

        half4 ak[4];
        ak[0] = __builtin_shufflevector(kkc0, kkc0, 0, 1, 2, 3);
        ak[1] = __builtin_shufflevector(kkc0, kkc0, 4, 5, 6, 7);
        ak[2] = __builtin_shufflevector(kkc1, kkc1, 0, 1, 2, 3);
        ak[3] = __builtin_shufflevector(kkc1, kkc1, 4, 5, 6, 7);

        // (2) prefetch kk(it+1) — consumed next iteration
        const int itn = (it < 15) ? it + 1 : 15;
        kkn0 = *(const half8*)(kfb + (size_t)itn * 1024);
        kkn1 = *(const half8*)(kfb + (size_t)itn * 1024 + 512);

        // (3) S(it): QK^T + exp + pack -> Pw
        floatx4 sf[4];
#pragma unroll
        for (int qt2 = 0; qt2 < 2; ++qt2) {
#pragma unroll
            for (int t = 0; t < 4; ++t)
                sf[t] = __builtin_amdgcn_mfma_f32_16x16x16f16(ak[t], bq4[qt2], zero4, 0, 0, 0);
            float rst[4];
            f16* Pq = Pw + qt2 * 1152 + n16 * PSTRIDE;
#pragma unroll
            for (int t = 0; t < 4; ++t) {
                float p0 = __builtin_exp2f(sf[t][0]);
                float p1 = __builtin_exp2f(sf[t][1]);
                float p2 = __builtin_exp2f(sf[t][2]);
                float p3 = __builtin_exp2f(sf[t][3]);
                rst[t] = (p0 + p1) + (p2 + p3);
                *(half4*)(Pq + t * 16 + quad * 4) = pack4(p0, p1, p2, p3);
            }
            l_loc[qt2] += (rst[0] + rst[1]) + (rst[2] + rst[3]);
        }

        // (4) PV(it-1): av loaded last iteration, bp read at (1)
#pragma unroll
        for (int qt2 = 0; qt2 < 2; ++qt2) {
#pragma unroll
            for (int ct = 0; ct < 4; ++ct)
                oacc[qt2][ct] = __builtin_amdgcn_mfma_f32_16x16x32_f16(av0[ct], bp[qt2][0], oacc[qt2][ct], 0, 0, 0);
#pragma unroll
            for (int ct = 0; ct < 4; ++ct)
                oacc[qt2][ct] = __builtin_amdgcn_mfma_f32_16x16x32_f16(av1[ct], bp[qt2][1], oacc[qt2][ct], 0, 0, 0);
        }

        // (5) issue av(it) — consumed by PV next iteration
#pragma unroll
        for (int ct = 0; ct < 4; ++ct)
            av0[ct] = *(const half8*)(vfb + ((size_t)(it * 2) * 4 + ct) * 512);
#pragma unroll
        for (int ct = 0; ct < 4; ++ct)
            av1[ct] = *(const half8*)(vfb + ((size_t)(it * 2 + 1) * 4 + ct) * 512);

        kkc0 = kkn0; kkc1 = kkn1;
    }

    // ---- tail: PV(15), P in buffer B ----
    {
        __asm__ volatile("s_waitcnt lgkmcnt(0)" ::: "memory");
        half8 bp[2][2];
#pragma unroll
        for (int qt2 = 0; qt2 < 2; ++qt2) {
            const f16* p = PB + qt2 * 1152 + n16 * PSTRIDE;
            bp[qt2][0] = *(const half8*)(p + quad * 8);
            bp[qt2][1] = *(const half8*)(p + 32 + quad * 8);
        }
#pragma unroll
        for (int qt2 = 0; qt2 < 2; ++qt2) {
#pragma unroll
            for (int ct = 0; ct < 4; ++ct)
                oacc[qt2][ct] = __builtin_amdgcn_mfma_f32_16x16x32_f16(av0[ct], bp[qt2][0], oacc[qt2][ct], 0, 0, 0);
#pragma unroll
            for (int ct = 0; ct < 4; ++ct)
                oacc[qt2][ct] = __builtin_amdgcn_mfma_f32_16x16x32_f16(av1[ct], bp[qt2][1], oacc[qt2][ct], 0, 0, 0);
        }
    }

    float l_run[2];
#pragma unroll
    for (int qt2 = 0; qt2 < 2; ++qt2) {
        float l = l_loc[qt2];
        l += __shfl_xor(l, 16, 64);
        l += __shfl_xor(l, 32, 64);
        l_run[qt2] = l;
    }

    __syncthreads();   // all P reads done; reuse smem as Obuf (f32, stride 20)
    if (ks > 0) {
#pragma unroll
        for (int qt2 = 0; qt2 < 2; ++qt2) {
            if (quad == 0) Ls[ks][qt2][n16] = l_run[qt2];
            float* ob = Obuf + (size_t)(((ks - 1) * 2 + qt2) * 64 + lane) * 20;
#pragma unroll
            for (int ct = 0; ct < 4; ++ct)
                *(floatx4*)(ob + ct * 4) = oacc[qt2][ct];
        }
    }
    __syncthreads();
    if (ks == 0) {
        const float g = gptr[0];
#pragma unroll
        for (int qt2 = 0; qt2 < 2; ++qt2) {
            float l = l_run[qt2];
            float o[16];
#pragma unroll
            for (int ct = 0; ct < 4; ++ct)
#pragma unroll
                for (int r = 0; r < 4; ++r) o[ct * 4 + r] = oacc[qt2][ct][r];
#pragma unroll
            for (int p = 1; p < 4; ++p) {
                l += Ls[p][qt2][n16];
                const float* ob = Obuf + (size_t)(((p - 1) * 2 + qt2) * 64 + lane) * 20;
#pragma unroll
                for (int ct = 0; ct < 4; ++ct) {
                    floatx4 t = *(const floatx4*)(ob + ct * 4);
                    o[ct * 4 + 0] += t[0]; o[ct * 4 + 1] += t[1];
                    o[ct * 4 + 2] += t[2]; o[ct * 4 + 3] += t[3];
                }
            }
            const float scale = g / l;
            const int q = qt * 32 + qt2 * 16 + n16;
#pragma unroll
            for (int ct = 0; ct < 4; ++ct) {
                const size_t idx = (bN + q) * CC + ct * 16 + quad * 4;
                float4 xr = *(const float4*)(x + idx);
                float4 res;
                res.x = o[ct * 4 + 0] * scale + xr.x;
                res.y = o[ct * 4 + 1] * scale + xr.y;
                res.z = o[ct * 4 + 2] * scale + xr.z;
                res.w = o[ct * 4 + 3] * scale + xr.w;
                *(float4*)(out + idx) = res;
            }
        }
    }
}

extern "C" void kernel_launch(void* const* d_in, const int* in_sizes, int n_in,
                              void* d_out, int out_size, void* d_ws, size_t ws_size,
                              hipStream_t stream) {
    const float* x     = (const float*)d_in[0];
    const float* wq    = (const float*)d_in[1];
    const float* bq    = (const float*)d_in[2];
    const float* wk    = (const float*)d_in[3];
    const float* bk    = (const float*)d_in[4];
    const float* wv    = (const float*)d_in[5];
    const float* bv    = (const float*)d_in[6];
    const float* gamma = (const float*)d_in[7];
    float* out = (float*)d_out;

    // ws: Qh 512KB | Kf 1MB | Vf 4MB | qn2 128KB | kn2 128KB | Mk2 32B
    f16* Qh = (f16*)d_ws;
    f16* Kf = Qh + (size_t)BB * NN * 8;
    f16* Vf = Kf + (size_t)BB * 128 * 512;
    float* qn2 = (float*)(Vf + (size_t)BB * 128 * 4 * 512);
    float* kn2 = qn2 + (size_t)BB * NN;
    float* Mk2 = kn2 + (size_t)BB * NN;

    proj_all_kernel<<<512, 256, 0, stream>>>(x, wq, bq, wk, bk, wv, bv,
                                             Qh, Kf, Vf, qn2, kn2);
    knorm_max_kernel<<<BB, 256, 0, stream>>>(kn2, Mk2);
    attn_kernel<<<BB * 128, 256, 0, stream>>>(Qh, Kf, Vf, qn2, Mk2, x, gamma, out);
}

// Round 2
// 126.561 us; speedup vs baseline: 1.0143x; 1.0068x over previous
//
#include <hip/hip_runtime.h>
#include <hip/hip_bf16.h>

// ConvSelfAttn: B=8, N=4096, C=64, d=8. FP32 I/O.
// R15: R14's software pipeline was correct but launch_bounds(256,4) forced a
// 64-arch-VGPR split -> ~28MB/dispatch scratch spill (WRITE_SIZE 8->27.6MB).
// Fix: launch_bounds(256,3) (R13's proven no-spill tier, ~168-reg budget) so
// the pipeline's ~130 live regs fit. Pipeline per iter: read bp(it-1) |
// QK^T(it) | prefetch kk(it+1) | exp/pack(it) | PV(it-1) | issue av(it).
// Obuf stride-20 epilogue kept from R14.

#define BB 8
#define NN 4096
#define CC 64
#define PSTRIDE 72
#define LOG2E 1.44269504088896f

typedef _Float16 f16;
typedef _Float16 half8 __attribute__((ext_vector_type(8)));
typedef _Float16 half4 __attribute__((ext_vector_type(4)));
typedef __fp16 fp16x2 __attribute__((ext_vector_type(2)));
typedef float floatx4 __attribute__((ext_vector_type(4)));

static __device__ inline half4 pack4(float a, float b, float c, float d) {
    fp16x2 lo = __builtin_amdgcn_cvt_pkrtz(a, b);
    fp16x2 hi = __builtin_amdgcn_cvt_pkrtz(c, d);
    unsigned int lou = __builtin_bit_cast(unsigned int, lo);
    unsigned int hiu = __builtin_bit_cast(unsigned int, hi);
    unsigned long long packed = (unsigned long long)lou | ((unsigned long long)hiu << 32);
    return __builtin_bit_cast(half4, packed);
}

// ws layouts (halfs):
//   Qh [B*N][8]                          Q pre-scaled by log2e
//   Kf [B][128 pair][64 lane][8]         pair-interleaved A-frags; halfs 0-3 =
//                                        even 16-key tile, 4-7 = odd; quad2 =
//                                        {1,0,0,0} (mf channel), quad3 = 0
//   Vf [B][128 kb32][4 ct][64 lane][8]   A-frags for 16x16x32 PV
//   qn2 [B*N] f32 | kn2 [B*N] f32 | Mk2 [B] f32

// ---------------- fused projection + fragment repack + norms ----------------
// grid 512 x 256 (4 waves x 16 pixels; block = 64 pixels of one batch)
__global__ __launch_bounds__(256) void proj_all_kernel(
    const float* __restrict__ x,
    const float* __restrict__ wq, const float* __restrict__ bq,
    const float* __restrict__ wk, const float* __restrict__ bk,
    const float* __restrict__ wv, const float* __restrict__ bv,
    f16* __restrict__ Qh, f16* __restrict__ Kf, f16* __restrict__ Vf,
    float* __restrict__ qn2, float* __restrict__ kn2)
{
    __shared__ alignas(16) f16 Ws[80][PSTRIDE];  // rows 0-63=V, 64-71=Q, 72-79=K
    __shared__ float Bs[80];
    __shared__ alignas(16) f16 Vs[64][68];       // [pixel][ch], pitch 68
    __shared__ alignas(16) f16 Ks[64][12];       // [pixel][ch]
    const int tid = threadIdx.x;

    for (int i = tid; i < 4096; i += 256) {
        int cin = i >> 6, cout = i & 63;
        Ws[cout][cin] = (f16)wv[i];
    }
    for (int i = tid; i < 512; i += 256) {
        int cin = i >> 3, c = i & 7;
        Ws[64 + c][cin] = (f16)(wq[i] * LOG2E);
        Ws[72 + c][cin] = (f16)wk[i];
    }
    if (tid < 80)
        Bs[tid] = (tid < 64) ? bv[tid]
                : (tid < 72 ? bq[tid - 64] * LOG2E : bk[tid - 72]);
    __syncthreads();

    const int wave = tid >> 6, lane = tid & 63;
    const int quad = lane >> 4, n16 = lane & 15;
    const long pb = (long)blockIdx.x * 64;
    const long p0 = pb + wave * 16;
    const int  b   = (int)(pb >> 12);
    const int  nnb = (int)(pb & 4095);

    half8 ax[2];
#pragma unroll
    for (int kh = 0; kh < 2; ++kh) {
        const float* xp = x + (p0 + n16) * 64 + kh * 32 + quad * 8;
        float4 x1 = *(const float4*)xp;
        float4 x2 = *(const float4*)(xp + 4);
        ax[kh][0] = (f16)x1.x; ax[kh][1] = (f16)x1.y;
        ax[kh][2] = (f16)x1.z; ax[kh][3] = (f16)x1.w;
        ax[kh][4] = (f16)x2.x; ax[kh][5] = (f16)x2.y;
        ax[kh][6] = (f16)x2.z; ax[kh][7] = (f16)x2.w;
    }

#pragma unroll
    for (int ct = 0; ct < 5; ++ct) {
        const int cout = (ct < 4) ? ct * 16 + n16 : 64 + n16;
        const float bias = Bs[cout];
        half8 b0 = *(const half8*)(&Ws[cout][quad * 8]);
        half8 b1 = *(const half8*)(&Ws[cout][32 + quad * 8]);
        floatx4 acc = {bias, bias, bias, bias};
        acc = __builtin_amdgcn_mfma_f32_16x16x32_f16(ax[0], b0, acc, 0, 0, 0);
        acc = __builtin_amdgcn_mfma_f32_16x16x32_f16(ax[1], b1, acc, 0, 0, 0);
        if (ct < 4) {
#pragma unroll
            for (int r = 0; r < 4; ++r)
                Vs[wave * 16 + quad * 4 + r][ct * 16 + n16] = (f16)acc[r];
        } else {
            float n2[4];
#pragma unroll
            for (int r = 0; r < 4; ++r) n2[r] = acc[r] * acc[r];
#pragma unroll
            for (int d = 1; d < 8; d <<= 1)
#pragma unroll
                for (int r = 0; r < 4; ++r) n2[r] += __shfl_xor(n2[r], d, 64);
            if (n16 == 0) {
#pragma unroll
                for (int r = 0; r < 4; ++r) qn2[p0 + quad * 4 + r] = n2[r];
            } else if (n16 == 8) {
#pragma unroll
                for (int r = 0; r < 4; ++r) kn2[p0 + quad * 4 + r] = n2[r];
            }
            if (n16 < 8) {
                f16* dst = Qh + (p0 + quad * 4) * 8 + n16;
#pragma unroll
                for (int r = 0; r < 4; ++r) dst[r * 8] = (f16)acc[r];
            } else {
#pragma unroll
                for (int r = 0; r < 4; ++r)
                    Ks[wave * 16 + quad * 4 + r][n16 - 8] = (f16)acc[r];
            }
        }
    }
    __syncthreads();

    // V fragment stores (2 tiles per wave), full 16B/lane
#pragma unroll
    for (int u = 0; u < 2; ++u) {
        const int tt = wave * 2 + u;
        const int kb = tt >> 2, ct = tt & 3;
        half8 v;
#pragma unroll
        for (int j = 0; j < 8; ++j)
            v[j] = Vs[kb * 32 + quad * 8 + j][ct * 16 + n16];
        const size_t kbg = (size_t)b * 128 + (nnb >> 5) + kb;
        *(half8*)(Vf + (kbg * 4 + ct) * 512 + lane * 8) = v;
    }
    // K pair-tile stores: waves 0-1 each store one pair as full 16B/lane lines
    if (wave < 2) {
        half8 kp;
#pragma unroll
        for (int e = 0; e < 2; ++e) {
            const int t = wave * 2 + e;
#pragma unroll
            for (int j = 0; j < 4; ++j) {
                f16 v = (f16)0.f;
                if (quad < 2) v = Ks[t * 16 + n16][quad * 4 + j];
                else if (quad == 2 && j == 0) v = (f16)1.f;  // mf ones channel
                kp[e * 4 + j] = v;
            }
        }
        const size_t kpg = (size_t)b * 128 + (nnb >> 5) + wave;
        *(half8*)(Kf + kpg * 512 + lane * 8) = kp;
    }
}

// ---------------- per-batch max key-norm reduce ----------------
__global__ __launch_bounds__(256) void knorm_max_kernel(
    const float* __restrict__ kn2, float* __restrict__ Mk2)
{
    __shared__ float red[4];
    const int b = blockIdx.x, tid = threadIdx.x;
    float mx = 0.f;
    for (int i = tid; i < NN; i += 256) mx = fmaxf(mx, kn2[(size_t)b * NN + i]);
#pragma unroll
    for (int d = 1; d < 64; d <<= 1) mx = fmaxf(mx, __shfl_xor(mx, d, 64));
    if ((tid & 63) == 0) red[tid >> 6] = mx;
    __syncthreads();
    if (tid == 0) Mk2[b] = fmaxf(fmaxf(red[0], red[1]), fmaxf(red[2], red[3]));
}

// ---------------- flash attention, static-max, 32 q/wave, key-split 4 ----------------
// grid B*128 = 1024 x 256 thr; wave = ks (0..3): keys [ks*1024,+1024), 16 iters.
// Pipeline per iter: read bp(it-1) | QK^T(it) | prefetch kk(it+1) |
// exp/pack(it) | PV(it-1) | issue av(it).  launch_bounds(256,3): no-spill tier.
__global__ __launch_bounds__(256, 3) void attn_kernel(
    const f16* __restrict__ Qh, const f16* __restrict__ Kf,
    const f16* __restrict__ Vf,
    const float* __restrict__ qn2, const float* __restrict__ Mk2,
    const float* __restrict__ x, const float* __restrict__ gptr,
    float* __restrict__ out)
{
    // smem union: two P buffers (2 x 18432B) during K-loop; Obuf (stride-20
    // f32, 30720B) after the barrier.
    __shared__ alignas(16) char smem[36864];
    __shared__ float Ls[4][2][16];
    f16*   Pbase = (f16*)smem;
    float* Obuf  = (float*)smem;

    const int tid  = threadIdx.x;
    const int wave = tid >> 6, lane = tid & 63;
    const int quad = lane >> 4, n16 = lane & 15;
    const int ks = wave;

    const int b  = blockIdx.x & 7;
    const int qt = blockIdx.x >> 3;               // 0..127 (32-query tile)
    const size_t bN = (size_t)b * NN;

    const float mk2 = Mk2[b];

    // Q B-frags: quads 0-1 = Q data; quad2 = {-mf,0,0,0}; quad3 = 0.
    half4 bq4[2];
#pragma unroll
    for (int qt2 = 0; qt2 < 2; ++qt2) {
        const int q = qt * 32 + qt2 * 16 + n16;
        const float mf = __builtin_sqrtf(qn2[bN + q] * mk2) - 12.0f;
        half4 v = {0, 0, 0, 0};
        if (quad < 2)
            v = *(const half4*)(Qh + (bN + q) * 8 + quad * 4);
        else if (quad == 2)
            v[0] = (f16)(-mf);
        bq4[qt2] = v;
    }

    floatx4 oacc[2][4];
#pragma unroll
    for (int qt2 = 0; qt2 < 2; ++qt2)
#pragma unroll
        for (int ct = 0; ct < 4; ++ct) oacc[qt2][ct] = (floatx4){0.f, 0.f, 0.f, 0.f};
    float l_loc[2] = {0.f, 0.f};

    const f16* kfb = Kf + ((size_t)b * 128 + ks * 32) * 512 + lane * 8;
    const f16* vfb = Vf + ((size_t)b * 128 + ks * 32) * 2048 + lane * 8;
    const floatx4 zero4 = {0.f, 0.f, 0.f, 0.f};

    // per-wave P regions: buffer A at [0,18432), buffer B at [18432,36864)
    f16* PA = Pbase + wave * 2304;
    f16* PB = Pbase + 9216 + wave * 2304;

    half8 kkc0 = *(const half8*)(kfb + 0);
    half8 kkc1 = *(const half8*)(kfb + 512);
    half8 av0[4], av1[4];

    // ---- iteration 0: S(0) -> PA; prefetch kk(1); issue av(0); no PV yet ----
    {
        half4 ak[4];
        ak[0] = __builtin_shufflevector(kkc0, kkc0, 0, 1, 2, 3);
        ak[1] = __builtin_shufflevector(kkc0, kkc0, 4, 5, 6, 7);
        ak[2] = __builtin_shufflevector(kkc1, kkc1, 0, 1, 2, 3);
        ak[3] = __builtin_shufflevector(kkc1, kkc1, 4, 5, 6, 7);

        kkc0 = *(const half8*)(kfb + 1024);
        kkc1 = *(const half8*)(kfb + 1536);
#pragma unroll
        for (int ct = 0; ct < 4; ++ct)
            av0[ct] = *(const half8*)(vfb + (size_t)ct * 512);
#pragma unroll
        for (int ct = 0; ct < 4; ++ct)
            av1[ct] = *(const half8*)(vfb + (size_t)(4 + ct) * 512);

        floatx4 sf[4];
#pragma unroll
        for (int qt2 = 0; qt2 < 2; ++qt2) {
#pragma unroll
            for (int t = 0; t < 4; ++t)
                sf[t] = __builtin_amdgcn_mfma_f32_16x16x16f16(ak[t], bq4[qt2], zero4, 0, 0, 0);
            float rst[4];
            f16* Pw = PA + qt2 * 1152 + n16 * PSTRIDE;
#pragma unroll
            for (int t = 0; t < 4; ++t) {
                float p0 = __builtin_exp2f(sf[t][0]);
                float p1 = __builtin_exp2f(sf[t][1]);
                float p2 = __builtin_exp2f(sf[t][2]);
                float p3 = __builtin_exp2f(sf[t][3]);
                rst[t] = (p0 + p1) + (p2 + p3);
                *(half4*)(Pw + t * 16 + quad * 4) = pack4(p0, p1, p2, p3);
            }
            l_loc[qt2] += (rst[0] + rst[1]) + (rst[2] + rst[3]);
        }
    }

    // ---- steady state: it = 1..15 ----
    for (int it = 1; it < 16; ++it) {
        f16* Pr = (it & 1) ? PA : PB;   // holds P(it-1)
        f16* Pw = (it & 1) ? PB : PA;   // receives P(it)

        // (1) read P(it-1) frags early; consumed by PV at (4)
        __asm__ volatile("s_waitcnt lgkmcnt(0)" ::: "memory");
        half8 bp[2][2];
#pragma unroll
        for (int qt2 = 0; qt2 < 2; ++qt2) {
            const f16* p = Pr + qt2 * 1152 + n16 * PSTRIDE;
            bp[qt2][0] = *(const half8*)(p + quad * 8);
            bp[qt2][1] = *(const half8*)(p + 32 + quad * 8);
        }

        half4 ak[4];
        ak[0] = __builtin_shufflevector(kkc0, kkc0, 0, 1, 2, 3);
        ak[1] = __builtin_shufflevector(kkc0, kkc0, 4, 5, 6, 7);
        ak[2] = __builtin_shufflevector(kkc1, kkc1, 0, 1, 2, 3);
        ak[3] = __builtin_shufflevector(kkc1, kkc1, 4, 5, 6, 7);

        // (2) prefetch kk(it+1) — consumed next iteration (in-place reload)
        const int itn = (it < 15) ? it + 1 : 15;
        kkc0 = *(const half8*)(kfb + (size_t)itn * 1024);
        kkc1 = *(const half8*)(kfb + (size_t)itn * 1024 + 512);

        // (3) S(it): QK^T + exp + pack -> Pw
        floatx4 sf[4];
#pragma unroll
        for (int qt2 = 0; qt2 < 2; ++qt2) {
#pragma unroll
            for (int t = 0; t < 4; ++t)
                sf[t] = __builtin_amdgcn_mfma_f32_16x16x16f16(ak[t], bq4[qt2], zero4, 0, 0, 0);
            float rst[4];
            f16* Pq = Pw + qt2 * 1152 + n16 * PSTRIDE;
#pragma unroll
            for (int t = 0; t < 4; ++t) {
                float p0 = __builtin_exp2f(sf[t][0]);
                float p1 = __builtin_exp2f(sf[t][1]);
                float p2 = __builtin_exp2f(sf[t][2]);
                float p3 = __builtin_exp2f(sf[t][3]);
                rst[t] = (p0 + p1) + (p2 + p3);
                *(half4*)(Pq + t * 16 + quad * 4) = pack4(p0, p1, p2, p3);
            }
            l_loc[qt2] += (rst[0] + rst[1]) + (rst[2] + rst[3]);
        }

        // (4) PV(it-1): av loaded last iteration, bp read at (1)
#pragma unroll
        for (int qt2 = 0; qt2 < 2; ++qt2) {
#pragma unroll
            for (int ct = 0; ct < 4; ++ct)
                oacc[qt2][ct] = __builtin_amdgcn_mfma_f32_16x16x32_f16(av0[ct], bp[qt2][0], oacc[qt2][ct], 0, 0, 0);
#pragma unroll
            for (int ct = 0; ct < 4; ++ct)
                oacc[qt2][ct] = __builtin_amdgcn_mfma_f32_16x16x32_f16(av1[ct], bp[qt2][1], oacc[qt2][ct], 0, 0, 0);
        }

        // (5) issue av(it) — consumed by PV next iteration
#pragma unroll
        for (int ct = 0; ct < 4; ++ct)
            av0[ct] = *(const half8*)(vfb + ((size_t)(it * 2) * 4 + ct) * 512);
#pragma unroll
        for (int ct = 0; ct < 4; ++ct)
            av1[ct] = *(const half8*)(vfb + ((size_t)(it * 2 + 1) * 4 + ct) * 512);
    }

    // ---- tail: PV(15), P in buffer B ----
    {
        __asm__ volatile("s_waitcnt lgkmcnt(0)" ::: "memory");
        half8 bp[2][2];
#pragma unroll
        for (int qt2 = 0; qt2 < 2; ++qt2) {
            const f16* p = PB + qt2 * 1152 + n16 * PSTRIDE;
            bp[qt2][0] = *(const half8*)(p + quad * 8);
            bp[qt2][1] = *(const half8*)(p + 32 + quad * 8);
        }
#pragma unroll
        for (int qt2 = 0; qt2 < 2; ++qt2) {
#pragma unroll
            for (int ct = 0; ct < 4; ++ct)
                oacc[qt2][ct] = __builtin_amdgcn_mfma_f32_16x16x32_f16(av0[ct], bp[qt2][0], oacc[qt2][ct], 0, 0, 0);
#pragma unroll
            for (int ct = 0; ct < 4; ++ct)
                oacc[qt2][ct] = __builtin_amdgcn_mfma_f32_16x16x32_f16(av1[ct], bp[qt2][1], oacc[qt2][ct], 0, 0, 0);
        }
    }

    float l_run[2];
#pragma unroll
    for (int qt2 = 0; qt2 < 2; ++qt2) {
        float l = l_loc[qt2];
        l += __shfl_xor(l, 16, 64);
        l += __shfl_xor(l, 32, 64);
        l_run[qt2] = l;
    }

    __syncthreads();   // all P reads done; reuse smem as Obuf (f32, stride 20)
    if (ks > 0) {
#pragma unroll
        for (int qt2 = 0; qt2 < 2; ++qt2) {
            if (quad == 0) Ls[ks][qt2][n16] = l_run[qt2];
            float* ob = Obuf + (size_t)(((ks - 1) * 2 + qt2) * 64 + lane) * 20;
#pragma unroll
            for (int ct = 0; ct < 4; ++ct)
                *(floatx4*)(ob + ct * 4) = oacc[qt2][ct];
        }
    }
    __syncthreads();
    if (ks == 0) {
        const float g = gptr[0];
#pragma unroll
        for (int qt2 = 0; qt2 < 2; ++qt2) {
            float l = l_run[qt2];
            float o[16];
#pragma unroll
            for (int ct = 0; ct < 4; ++ct)
#pragma unroll
                for (int r = 0; r < 4; ++r) o[ct * 4 + r] = oacc[qt2][ct][r];
#pragma unroll
            for (int p = 1; p < 4; ++p) {
                l += Ls[p][qt2][n16];
                const float* ob = Obuf + (size_t)(((p - 1) * 2 + qt2) * 64 + lane) * 20;
#pragma unroll
                for (int ct = 0; ct < 4; ++ct) {
                    floatx4 t = *(const floatx4*)(ob + ct * 4);
                    o[ct * 4 + 0] += t[0]; o[ct * 4 + 1] += t[1];
                    o[ct * 4 + 2] += t[2]; o[ct * 4 + 3] += t[3];
                }
            }
            const float scale = g / l;
            const int q = qt * 32 + qt2 * 16 + n16;
#pragma unroll
            for (int ct = 0; ct < 4; ++ct) {
                const size_t idx = (bN + q) * CC + ct * 16 + quad * 4;
                float4 xr = *(const float4*)(x + idx);
                float4 res;
                res.x = o[ct * 4 + 0] * scale + xr.x;
                res.y = o[ct * 4 + 1] * scale + xr.y;
                res.z = o[ct * 4 + 2] * scale + xr.z;
                res.w = o[ct * 4 + 3] * scale + xr.w;
                *(float4*)(out + idx) = res;
            }
        }
    }
}

extern "C" void kernel_launch(void* const* d_in, const int* in_sizes, int n_in,
                              void* d_out, int out_size, void* d_ws, size_t ws_size,
                              hipStream_t stream) {
    const float* x     = (const float*)d_in[0];
    const float* wq    = (const float*)d_in[1];
    const float* bq    = (const float*)d_in[2];
    const float* wk    = (const float*)d_in[3];
    const float* bk    = (const float*)d_in[4];
    const float* wv    = (const float*)d_in[5];
    const float* bv    = (const float*)d_in[6];
    const float* gamma = (const float*)d_in[7];
    float* out = (float*)d_out;

    // ws: Qh 512KB | Kf 1MB | Vf 4MB | qn2 128KB | kn2 128KB | Mk2 32B
    f16* Qh = (f16*)d_ws;
    f16* Kf = Qh + (size_t)BB * NN * 8;
    f16* Vf = Kf + (size_t)BB * 128 * 512;
    float* qn2 = (float*)(Vf + (size_t)BB * 128 * 4 * 512);
    float* kn2 = qn2 + (size_t)BB * NN;
    float* Mk2 = kn2 + (size_t)BB * NN;

    proj_all_kernel<<<512, 256, 0, stream>>>(x, wq, bq, wk, bk, wv, bv,
                                             Qh, Kf, Vf, qn2, kn2);
    knorm_max_kernel<<<BB, 256, 0, stream>>>(kn2, Mk2);
    attn_kernel<<<BB * 128, 256, 0, stream>>>(Qh, Kf, Vf, qn2, Mk2, x, gamma, out);
}

// Round 3
// 123.933 us; speedup vs baseline: 1.0358x; 1.0212x over previous
//
#include <hip/hip_runtime.h>
#include <hip/hip_bf16.h>

// ConvSelfAttn: B=8, N=4096, C=64, d=8. FP32 I/O.
// R16: delete the P LDS round trip entirely. Key fact: the 16x16x16 MFMA
// B-frag layout (col=lane&15, k=quad*4+j) IS the QK^T C-frag layout
// (col=query, row=quad*4+reg=key). So PV switches from 16x16x32 (which
// needed k=quad*8+j, forcing a pack->ds_write->ds_read transpose) to
// 16x16x16 with B = pack4(sf[t]) straight from registers. Vf is re-laid in
// proj as 16-key-tile A-frags (V[32p+16h+4q+j][16ct+n16], even/odd tile in
// low/high half8). oacc layout is unchanged -> epilogue identical.
// Loop is the simple R13 shape (R14/R15 hand pipeline was net-negative) with
// 1-deep kk prefetch. LDS in the K-loop: zero. Obuf stride-20 kept.

#define BB 8
#define NN 4096
#define CC 64
#define PSTRIDE 72
#define LOG2E 1.44269504088896f

typedef _Float16 f16;
typedef _Float16 half8 __attribute__((ext_vector_type(8)));
typedef _Float16 half4 __attribute__((ext_vector_type(4)));
typedef __fp16 fp16x2 __attribute__((ext_vector_type(2)));
typedef float floatx4 __attribute__((ext_vector_type(4)));

static __device__ inline half4 pack4(float a, float b, float c, float d) {
    fp16x2 lo = __builtin_amdgcn_cvt_pkrtz(a, b);
    fp16x2 hi = __builtin_amdgcn_cvt_pkrtz(c, d);
    unsigned int lou = __builtin_bit_cast(unsigned int, lo);
    unsigned int hiu = __builtin_bit_cast(unsigned int, hi);
    unsigned long long packed = (unsigned long long)lou | ((unsigned long long)hiu << 32);
    return __builtin_bit_cast(half4, packed);
}

// ws layouts (halfs):
//   Qh [B*N][8]                          Q pre-scaled by log2e
//   Kf [B][128 pair][64 lane][8]         pair-interleaved QK A-frags; halfs
//                                        0-3 = even 16-key tile, 4-7 = odd;
//                                        quad2 = {1,0,0,0} (mf), quad3 = 0
//   Vf [B][128 pair][4 ct][64 lane][8]   16x16x16 PV A-frags; halfs 0-3 =
//                                        even 16-key tile (V[32p+4q+j][c]),
//                                        4-7 = odd tile (V[32p+16+4q+j][c])
//   qn2 [B*N] f32 | kn2 [B*N] f32 | Mk2 [B] f32

// ---------------- fused projection + fragment repack + norms ----------------
// grid 512 x 256 (4 waves x 16 pixels; block = 64 pixels of one batch)
__global__ __launch_bounds__(256) void proj_all_kernel(
    const float* __restrict__ x,
    const float* __restrict__ wq, const float* __restrict__ bq,
    const float* __restrict__ wk, const float* __restrict__ bk,
    const float* __restrict__ wv, const float* __restrict__ bv,
    f16* __restrict__ Qh, f16* __restrict__ Kf, f16* __restrict__ Vf,
    float* __restrict__ qn2, float* __restrict__ kn2)
{
    __shared__ alignas(16) f16 Ws[80][PSTRIDE];  // rows 0-63=V, 64-71=Q, 72-79=K
    __shared__ float Bs[80];
    __shared__ alignas(16) f16 Vs[64][68];       // [pixel][ch], pitch 68
    __shared__ alignas(16) f16 Ks[64][12];       // [pixel][ch]
    const int tid = threadIdx.x;

    for (int i = tid; i < 4096; i += 256) {
        int cin = i >> 6, cout = i & 63;
        Ws[cout][cin] = (f16)wv[i];
    }
    for (int i = tid; i < 512; i += 256) {
        int cin = i >> 3, c = i & 7;
        Ws[64 + c][cin] = (f16)(wq[i] * LOG2E);
        Ws[72 + c][cin] = (f16)wk[i];
    }
    if (tid < 80)
        Bs[tid] = (tid < 64) ? bv[tid]
                : (tid < 72 ? bq[tid - 64] * LOG2E : bk[tid - 72]);
    __syncthreads();

    const int wave = tid >> 6, lane = tid & 63;
    const int quad = lane >> 4, n16 = lane & 15;
    const long pb = (long)blockIdx.x * 64;
    const long p0 = pb + wave * 16;
    const int  b   = (int)(pb >> 12);
    const int  nnb = (int)(pb & 4095);

    half8 ax[2];
#pragma unroll
    for (int kh = 0; kh < 2; ++kh) {
        const float* xp = x + (p0 + n16) * 64 + kh * 32 + quad * 8;
        float4 x1 = *(const float4*)xp;
        float4 x2 = *(const float4*)(xp + 4);
        ax[kh][0] = (f16)x1.x; ax[kh][1] = (f16)x1.y;
        ax[kh][2] = (f16)x1.z; ax[kh][3] = (f16)x1.w;
        ax[kh][4] = (f16)x2.x; ax[kh][5] = (f16)x2.y;
        ax[kh][6] = (f16)x2.z; ax[kh][7] = (f16)x2.w;
    }

#pragma unroll
    for (int ct = 0; ct < 5; ++ct) {
        const int cout = (ct < 4) ? ct * 16 + n16 : 64 + n16;
        const float bias = Bs[cout];
        half8 b0 = *(const half8*)(&Ws[cout][quad * 8]);
        half8 b1 = *(const half8*)(&Ws[cout][32 + quad * 8]);
        floatx4 acc = {bias, bias, bias, bias};
        acc = __builtin_amdgcn_mfma_f32_16x16x32_f16(ax[0], b0, acc, 0, 0, 0);
        acc = __builtin_amdgcn_mfma_f32_16x16x32_f16(ax[1], b1, acc, 0, 0, 0);
        if (ct < 4) {
#pragma unroll
            for (int r = 0; r < 4; ++r)
                Vs[wave * 16 + quad * 4 + r][ct * 16 + n16] = (f16)acc[r];
        } else {
            float n2[4];
#pragma unroll
            for (int r = 0; r < 4; ++r) n2[r] = acc[r] * acc[r];
#pragma unroll
            for (int d = 1; d < 8; d <<= 1)
#pragma unroll
                for (int r = 0; r < 4; ++r) n2[r] += __shfl_xor(n2[r], d, 64);
            if (n16 == 0) {
#pragma unroll
                for (int r = 0; r < 4; ++r) qn2[p0 + quad * 4 + r] = n2[r];
            } else if (n16 == 8) {
#pragma unroll
                for (int r = 0; r < 4; ++r) kn2[p0 + quad * 4 + r] = n2[r];
            }
            if (n16 < 8) {
                f16* dst = Qh + (p0 + quad * 4) * 8 + n16;
#pragma unroll
                for (int r = 0; r < 4; ++r) dst[r * 8] = (f16)acc[r];
            } else {
#pragma unroll
                for (int r = 0; r < 4; ++r)
                    Ks[wave * 16 + quad * 4 + r][n16 - 8] = (f16)acc[r];
            }
        }
    }
    __syncthreads();

    // V fragment stores (2 tiles per wave), 16x16x16 A-frag pair layout:
    // halfs 0-3 = even 16-key tile, 4-7 = odd tile of this 32-key pair.
#pragma unroll
    for (int u = 0; u < 2; ++u) {
        const int tt = wave * 2 + u;
        const int kb = tt >> 2, ct = tt & 3;
        half8 v;
#pragma unroll
        for (int j = 0; j < 4; ++j)
            v[j] = Vs[kb * 32 + quad * 4 + j][ct * 16 + n16];
#pragma unroll
        for (int j = 0; j < 4; ++j)
            v[4 + j] = Vs[kb * 32 + 16 + quad * 4 + j][ct * 16 + n16];
        const size_t kbg = (size_t)b * 128 + (nnb >> 5) + kb;
        *(half8*)(Vf + (kbg * 4 + ct) * 512 + lane * 8) = v;
    }
    // K pair-tile stores: waves 0-1 each store one pair as full 16B/lane lines
    if (wave < 2) {
        half8 kp;
#pragma unroll
        for (int e = 0; e < 2; ++e) {
            const int t = wave * 2 + e;
#pragma unroll
            for (int j = 0; j < 4; ++j) {
                f16 v = (f16)0.f;
                if (quad < 2) v = Ks[t * 16 + n16][quad * 4 + j];
                else if (quad == 2 && j == 0) v = (f16)1.f;  // mf ones channel
                kp[e * 4 + j] = v;
            }
        }
        const size_t kpg = (size_t)b * 128 + (nnb >> 5) + wave;
        *(half8*)(Kf + kpg * 512 + lane * 8) = kp;
    }
}

// ---------------- per-batch max key-norm reduce ----------------
__global__ __launch_bounds__(256) void knorm_max_kernel(
    const float* __restrict__ kn2, float* __restrict__ Mk2)
{
    __shared__ float red[4];
    const int b = blockIdx.x, tid = threadIdx.x;
    float mx = 0.f;
    for (int i = tid; i < NN; i += 256) mx = fmaxf(mx, kn2[(size_t)b * NN + i]);
#pragma unroll
    for (int d = 1; d < 64; d <<= 1) mx = fmaxf(mx, __shfl_xor(mx, d, 64));
    if ((tid & 63) == 0) red[tid >> 6] = mx;
    __syncthreads();
    if (tid == 0) Mk2[b] = fmaxf(fmaxf(red[0], red[1]), fmaxf(red[2], red[3]));
}

// ---------------- flash attention, static-max, 32 q/wave, key-split 4 ----------------
// grid B*128 = 1024 x 256 thr; wave = ks (0..3): keys [ks*1024,+1024), 16 iters
// of 64 keys. P never touches LDS: PV = 16x16x16 MFMAs with B = pack4(sf[t]).
__global__ __launch_bounds__(256, 3) void attn_kernel(
    const f16* __restrict__ Qh, const f16* __restrict__ Kf,
    const f16* __restrict__ Vf,
    const float* __restrict__ qn2, const float* __restrict__ Mk2,
    const float* __restrict__ x, const float* __restrict__ gptr,
    float* __restrict__ out)
{
    // smem: Obuf only (f32, stride 20, 3 partial ks x 2 qt2 x 64 lanes x 16ch)
    __shared__ alignas(16) char smem[30720];
    __shared__ float Ls[4][2][16];
    float* Obuf = (float*)smem;

    const int tid  = threadIdx.x;
    const int wave = tid >> 6, lane = tid & 63;
    const int quad = lane >> 4, n16 = lane & 15;
    const int ks = wave;

    const int b  = blockIdx.x & 7;
    const int qt = blockIdx.x >> 3;               // 0..127 (32-query tile)
    const size_t bN = (size_t)b * NN;

    const float mk2 = Mk2[b];

    // Q B-frags: quads 0-1 = Q data; quad2 = {-mf,0,0,0}; quad3 = 0.
    half4 bq4[2];
#pragma unroll
    for (int qt2 = 0; qt2 < 2; ++qt2) {
        const int q = qt * 32 + qt2 * 16 + n16;
        const float mf = __builtin_sqrtf(qn2[bN + q] * mk2) - 12.0f;
        half4 v = {0, 0, 0, 0};
        if (quad < 2)
            v = *(const half4*)(Qh + (bN + q) * 8 + quad * 4);
        else if (quad == 2)
            v[0] = (f16)(-mf);
        bq4[qt2] = v;
    }

    floatx4 oacc[2][4];
#pragma unroll
    for (int qt2 = 0; qt2 < 2; ++qt2)
#pragma unroll
        for (int ct = 0; ct < 4; ++ct) oacc[qt2][ct] = (floatx4){0.f, 0.f, 0.f, 0.f};
    float l_loc[2] = {0.f, 0.f};

    const f16* kfb = Kf + ((size_t)b * 128 + ks * 32) * 512 + lane * 8;
    const f16* vfb = Vf + ((size_t)b * 128 + ks * 32) * 2048 + lane * 8;
    const floatx4 zero4 = {0.f, 0.f, 0.f, 0.f};

    half8 kkc0 = *(const half8*)(kfb + 0);
    half8 kkc1 = *(const half8*)(kfb + 512);

    for (int it = 0; it < 16; ++it) {
        // V A-frag pair loads for this iteration's 64 keys (2 pairs x 4 ct)
        half8 avp[2][4];
#pragma unroll
        for (int p = 0; p < 2; ++p)
#pragma unroll
            for (int ct = 0; ct < 4; ++ct)
                avp[p][ct] = *(const half8*)(vfb + ((size_t)(it * 2 + p) * 4 + ct) * 512);

        half4 ak[4];
        ak[0] = __builtin_shufflevector(kkc0, kkc0, 0, 1, 2, 3);
        ak[1] = __builtin_shufflevector(kkc0, kkc0, 4, 5, 6, 7);
        ak[2] = __builtin_shufflevector(kkc1, kkc1, 0, 1, 2, 3);
        ak[3] = __builtin_shufflevector(kkc1, kkc1, 4, 5, 6, 7);

        // prefetch kk(it+1)
        const int itn = (it < 15) ? it + 1 : 15;
        kkc0 = *(const half8*)(kfb + (size_t)itn * 1024);
        kkc1 = *(const half8*)(kfb + (size_t)itn * 1024 + 512);

#pragma unroll
        for (int qt2 = 0; qt2 < 2; ++qt2) {
            floatx4 sf[4];
#pragma unroll
            for (int t = 0; t < 4; ++t)
                sf[t] = __builtin_amdgcn_mfma_f32_16x16x16f16(ak[t], bq4[qt2], zero4, 0, 0, 0);

            half4 pk[4];
            float rst[4];
#pragma unroll
            for (int t = 0; t < 4; ++t) {
                float p0 = __builtin_exp2f(sf[t][0]);
                float p1 = __builtin_exp2f(sf[t][1]);
                float p2 = __builtin_exp2f(sf[t][2]);
                float p3 = __builtin_exp2f(sf[t][3]);
                rst[t] = (p0 + p1) + (p2 + p3);
                pk[t] = pack4(p0, p1, p2, p3);
            }
            l_loc[qt2] += (rst[0] + rst[1]) + (rst[2] + rst[3]);

            // PV: 16x16x16, A = V tile frag (even/odd half of pair), B = pk[t]
#pragma unroll
            for (int t = 0; t < 4; ++t) {
                const int p = t >> 1;
#pragma unroll
                for (int ct = 0; ct < 4; ++ct) {
                    half4 va = (t & 1)
                        ? __builtin_shufflevector(avp[p][ct], avp[p][ct], 4, 5, 6, 7)
                        : __builtin_shufflevector(avp[p][ct], avp[p][ct], 0, 1, 2, 3);
                    oacc[qt2][ct] = __builtin_amdgcn_mfma_f32_16x16x16f16(va, pk[t], oacc[qt2][ct], 0, 0, 0);
                }
            }
        }
    }

    float l_run[2];
#pragma unroll
    for (int qt2 = 0; qt2 < 2; ++qt2) {
        float l = l_loc[qt2];
        l += __shfl_xor(l, 16, 64);
        l += __shfl_xor(l, 32, 64);
        l_run[qt2] = l;
    }

    __syncthreads();   // Obuf combine (f32, stride 20)
    if (ks > 0) {
#pragma unroll
        for (int qt2 = 0; qt2 < 2; ++qt2) {
            if (quad == 0) Ls[ks][qt2][n16] = l_run[qt2];
            float* ob = Obuf + (size_t)(((ks - 1) * 2 + qt2) * 64 + lane) * 20;
#pragma unroll
            for (int ct = 0; ct < 4; ++ct)
                *(floatx4*)(ob + ct * 4) = oacc[qt2][ct];
        }
    }
    __syncthreads();
    if (ks == 0) {
        const float g = gptr[0];
#pragma unroll
        for (int qt2 = 0; qt2 < 2; ++qt2) {
            float l = l_run[qt2];
            float o[16];
#pragma unroll
            for (int ct = 0; ct < 4; ++ct)
#pragma unroll
                for (int r = 0; r < 4; ++r) o[ct * 4 + r] = oacc[qt2][ct][r];
#pragma unroll
            for (int p = 1; p < 4; ++p) {
                l += Ls[p][qt2][n16];
                const float* ob = Obuf + (size_t)(((p - 1) * 2 + qt2) * 64 + lane) * 20;
#pragma unroll
                for (int ct = 0; ct < 4; ++ct) {
                    floatx4 t = *(const floatx4*)(ob + ct * 4);
                    o[ct * 4 + 0] += t[0]; o[ct * 4 + 1] += t[1];
                    o[ct * 4 + 2] += t[2]; o[ct * 4 + 3] += t[3];
                }
            }
            const float scale = g / l;
            const int q = qt * 32 + qt2 * 16 + n16;
#pragma unroll
            for (int ct = 0; ct < 4; ++ct) {
                const size_t idx = (bN + q) * CC + ct * 16 + quad * 4;
                float4 xr = *(const float4*)(x + idx);
                float4 res;
                res.x = o[ct * 4 + 0] * scale + xr.x;
                res.y = o[ct * 4 + 1] * scale + xr.y;
                res.z = o[ct * 4 + 2] * scale + xr.z;
                res.w = o[ct * 4 + 3] * scale + xr.w;
                *(float4*)(out + idx) = res;
            }
        }
    }
}

extern "C" void kernel_launch(void* const* d_in, const int* in_sizes, int n_in,
                              void* d_out, int out_size, void* d_ws, size_t ws_size,
                              hipStream_t stream) {
    const float* x     = (const float*)d_in[0];
    const float* wq    = (const float*)d_in[1];
    const float* bq    = (const float*)d_in[2];
    const float* wk    = (const float*)d_in[3];
    const float* bk    = (const float*)d_in[4];
    const float* wv    = (const float*)d_in[5];
    const float* bv    = (const float*)d_in[6];
    const float* gamma = (const float*)d_in[7];
    float* out = (float*)d_out;

    // ws: Qh 512KB | Kf 1MB | Vf 4MB | qn2 128KB | kn2 128KB | Mk2 32B
    f16* Qh = (f16*)d_ws;
    f16* Kf = Qh + (size_t)BB * NN * 8;
    f16* Vf = Kf + (size_t)BB * 128 * 512;
    float* qn2 = (float*)(Vf + (size_t)BB * 128 * 4 * 512);
    float* kn2 = qn2 + (size_t)BB * NN;
    float* Mk2 = kn2 + (size_t)BB * NN;

    proj_all_kernel<<<512, 256, 0, stream>>>(x, wq, bq, wk, bk, wv, bv,
                                             Qh, Kf, Vf, qn2, kn2);
    knorm_max_kernel<<<BB, 256, 0, stream>>>(kn2, Mk2);
    attn_kernel<<<BB * 128, 256, 0, stream>>>(Qh, Kf, Vf, qn2, Mk2, x, gamma, out);
}